// Round 14
// baseline (804.260 us; speedup 1.0000x reference)
//
#include <hip/hip_runtime.h>
#include <stdint.h>

#define NB 32      // B
#define NT 256     // T
#define NS 32      // S
#define NH 512     // H
#define NV 128     // V
#define BT 8192    // B*T

typedef __attribute__((ext_vector_type(8))) __bf16 bf16x8;
typedef __attribute__((ext_vector_type(4))) float f32x4;
typedef __attribute__((ext_vector_type(2))) _Float16 half2v;
typedef unsigned long long u64;

typedef __attribute__((address_space(1))) const unsigned int GASU;
typedef __attribute__((address_space(3))) unsigned int LASU;
#define ASYNC16(g, l) __builtin_amdgcn_global_load_lds((GASU*)(g), (LASU*)(l), 16, 0, 0)

__device__ __forceinline__ half2v pkrtz(float a, float b){
  return __builtin_bit_cast(half2v, __builtin_amdgcn_cvt_pkrtz(a, b));
}
__device__ __forceinline__ unsigned short f2bf(float f){
  unsigned int u = __builtin_bit_cast(unsigned int, f);
  u += 0x7fffu + ((u >> 16) & 1u);
  return (unsigned short)(u >> 16);
}
__device__ __forceinline__ float bf2f(unsigned short h){
  return __builtin_bit_cast(float, ((unsigned int)h) << 16);
}
__device__ __forceinline__ float fexp(float x){ return __builtin_amdgcn_exp2f(x * 1.4426950408889634f); }
__device__ __forceinline__ float fsigm(float x){ return __builtin_amdgcn_rcpf(1.f + fexp(-x)); }
__device__ __forceinline__ float ftanh(float x){
  float t = __builtin_amdgcn_exp2f(x * 2.8853900817779268f);
  return (t - 1.f) * __builtin_amdgcn_rcpf(t + 1.f);
}
__device__ __forceinline__ float flog(float x){ return __builtin_amdgcn_logf(x) * 0.6931471805599453f; }

// L2 fast-path store: plain store (lands in the producer XCD's L2).
__device__ __forceinline__ void st_l2(u64* p, u64 v){
  asm volatile("global_store_dwordx2 %0, %1, off" :: "v"(p), "v"(v) : "memory");
}

// barrier WITHOUT the vmcnt(0) drain __syncthreads would emit (rule #18 fenced)
#define BAR() do{ \
  asm volatile("s_waitcnt lgkmcnt(0)" ::: "memory"); \
  __builtin_amdgcn_sched_barrier(0); \
  __builtin_amdgcn_s_barrier(); \
  __builtin_amdgcn_sched_barrier(0); \
}while(0)

// ------ fp32 -> bf16 conversions of tables/weights + init duties (merged) ------
__global__ void k_prep(const float* __restrict__ emb, const float* __restrict__ scope,
                       const float* __restrict__ Wih, const float* __restrict__ Wout,
                       const float* __restrict__ Wd,  const float* __restrict__ We,
                       unsigned short* e_o, unsigned short* s_o, unsigned short* wi_o,
                       unsigned short* wo_o, unsigned short* wd_o, unsigned short* we_o,
                       u64* hx, u64* hxL, float* out){
  int g = blockIdx.x*256 + threadIdx.x, gs = gridDim.x*256;
  if (g < 2*NB*256){
    hx[g] = 0ull;
    __hip_atomic_store(hxL + g, 0ull, __ATOMIC_RELAXED, __HIP_MEMORY_SCOPE_AGENT);
  }
  if (g < NB) out[g] = 0.f;
  for (int i=g; i<NV*NH;      i+=gs) e_o[i]  = f2bf(emb[i]);
  for (int i=g; i<NB*NS*NH;   i+=gs) s_o[i]  = f2bf(scope[i]);
  for (int i=g; i<3*NH*2*NH;  i+=gs) wi_o[i] = f2bf(Wih[i]);
  for (int i=g; i<NV*NH;      i+=gs) wo_o[i] = f2bf(Wout[i]);
  for (int i=g; i<NH*NH;      i+=gs) wd_o[i] = f2bf(Wd[i]);
  for (int i=g; i<NH*NH;      i+=gs) we_o[i] = f2bf(We[i]);
}

// ---------------- h0 = spec_enc @ W_init^T + b_init ----------------------------
__global__ void k_h0(const float* __restrict__ spec, const float* __restrict__ Winit,
                     const float* __restrict__ binit, float* __restrict__ h032,
                     u64* __restrict__ hx, u64* __restrict__ hxL){
  const int b = blockIdx.x, tid = threadIdx.x, lane = tid & 63, w = tid >> 6;
  __shared__ float sp[NH];
  __shared__ float hres[NH];
  if (tid < 128) *(float4*)&sp[tid*4] = *(const float4*)(spec + b*NH + tid*4);
  __syncthreads();
  for (int i = 0; i < 128; ++i){
    int j = w * 128 + i;
    const float4* wr = (const float4*)(Winit + (size_t)j * NH);
    float4 x0 = wr[lane*2], x1 = wr[lane*2 + 1];
    float p = x0.x*sp[lane*8]   + x0.y*sp[lane*8+1] + x0.z*sp[lane*8+2] + x0.w*sp[lane*8+3]
            + x1.x*sp[lane*8+4] + x1.y*sp[lane*8+5] + x1.z*sp[lane*8+6] + x1.w*sp[lane*8+7];
    #pragma unroll
    for (int o = 1; o < 64; o <<= 1) p += __shfl_xor(p, o);
    if (lane == 0){
      float v = p + binit[j];
      h032[b*NH + j] = v;
      hres[j] = v;
    }
  }
  __syncthreads();
  if (tid < 256){
    unsigned int pw = __builtin_bit_cast(unsigned int, pkrtz(hres[2*tid], hres[2*tid+1]));
    u64 pv = (1ull << 32) | (u64)pw;           // tag(h_0) = 1
    __hip_atomic_store(hx + b*256 + tid, pv, __ATOMIC_RELAXED, __HIP_MEMORY_SCOPE_AGENT);
    __hip_atomic_store(hxL + b*256 + tid, pv, __ATOMIC_RELAXED, __HIP_MEMORY_SCOPE_AGENT);
  }
}

// ------- MFMA bf16 GEMM: C = A @ Bw^T (+bias), 128x128 tile, B row-stride ldb --
__global__ __launch_bounds__(256, 2) void k_gemm(
    const unsigned short* __restrict__ A, const unsigned short* __restrict__ Bw,
    float* __restrict__ Cf, unsigned short* __restrict__ Cbf,
    const float* __restrict__ bias, int M, int N, int K, int ldb)
{
  __shared__ unsigned short lA[2][128][64];
  __shared__ unsigned short lB[2][128][64];
  const int tid = threadIdx.x, lane = tid & 63, wv = tid >> 6;
  const int m0 = blockIdx.x * 128, n0 = blockIdx.y * 128;

  const unsigned short* srcA[4];
  const unsigned short* srcB[4];
  #pragma unroll
  for (int i = 0; i < 4; ++i){
    int ar = m0 + wv*32 + i*8 + (lane >> 3);
    int chunk = (lane & 7) * 8;
    srcA[i] = A + (size_t)ar * K + chunk;
    int br = n0 + wv*32 + i*8 + (lane >> 3);
    srcB[i] = Bw + (size_t)br * ldb + chunk;
  }

  f32x4 acc[4][4];
  #pragma unroll
  for (int x=0;x<4;++x)
    #pragma unroll
    for (int y=0;y<4;++y) acc[x][y] = (f32x4){0.f,0.f,0.f,0.f};

  auto STAGE = [&](int bf, int kt){
    const int k0 = kt * 64;
    #pragma unroll
    for (int i = 0; i < 4; ++i){
      ASYNC16(srcA[i] + k0, &lA[bf][wv*32 + i*8][0]);
      ASYNC16(srcB[i] + k0, &lB[bf][wv*32 + i*8][0]);
    }
  };

  STAGE(0, 0);
  asm volatile("s_waitcnt vmcnt(0)" ::: "memory");
  __syncthreads();

  const int wm = (wv >> 1) * 64, wn = (wv & 1) * 64;
  const int fr = lane & 15, fq = lane >> 4;
  const int nt = K >> 6;
  int cur = 0;
  for (int kt = 0; kt < nt; ++kt){
    if (kt + 1 < nt) STAGE(cur ^ 1, kt + 1);
    #pragma unroll
    for (int ks = 0; ks < 2; ++ks){
      bf16x8 af[4], bfv[4];
      #pragma unroll
      for (int mi = 0; mi < 4; ++mi)
        af[mi] = *(const bf16x8*)&lA[cur][wm + mi*16 + fr][ks*32 + fq*8];
      #pragma unroll
      for (int ni = 0; ni < 4; ++ni)
        bfv[ni] = *(const bf16x8*)&lB[cur][wn + ni*16 + fr][ks*32 + fq*8];
      #pragma unroll
      for (int mi = 0; mi < 4; ++mi)
        #pragma unroll
        for (int ni = 0; ni < 4; ++ni)
          acc[mi][ni] = __builtin_amdgcn_mfma_f32_16x16x32_bf16(af[mi], bfv[ni], acc[mi][ni], 0, 0, 0);
    }
    asm volatile("s_waitcnt vmcnt(0)" ::: "memory");
    __syncthreads();
    cur ^= 1;
  }

  #pragma unroll
  for (int mi = 0; mi < 4; ++mi){
    #pragma unroll
    for (int ni = 0; ni < 4; ++ni){
      int col = n0 + wn + ni*16 + fr;
      float bv = bias ? bias[col] : 0.f;
      #pragma unroll
      for (int rr = 0; rr < 4; ++rr){
        int row = m0 + wm + mi*16 + fq*4 + rr;
        float v = acc[mi][ni][rr] + bv;
        if (Cbf) Cbf[(size_t)row * N + col] = f2bf(v);
        else     Cf [(size_t)row * N + col] = v;
      }
    }
  }
}

// ------ FUSED logits GEMM + log-softmax + target gather + per-batch sum --------
// One block = 128 rows x all 128 cols (NV=128). Epilogue computes row LSE via
// 16-lane-group shfl reduces + cross-wave LDS combine, gathers the target
// logit, and atomicAdds sum(tok_ll) for the rows into out[b].
__global__ __launch_bounds__(256, 2) void k_logll(
    const unsigned short* __restrict__ A, const unsigned short* __restrict__ Bw,
    const float* __restrict__ bias, const int* __restrict__ tko,
    float* __restrict__ out)
{
  __shared__ unsigned short lA[2][128][64];
  __shared__ unsigned short lB[2][128][64];
  __shared__ float pmax[128][2], psum[128][2], tgt[128], part[2];
  const int tid = threadIdx.x, lane = tid & 63, wv = tid >> 6;
  const int m0 = blockIdx.x * 128;

  const unsigned short* srcA[4];
  const unsigned short* srcB[4];
  #pragma unroll
  for (int i = 0; i < 4; ++i){
    int ar = m0 + wv*32 + i*8 + (lane >> 3);
    int chunk = (lane & 7) * 8;
    srcA[i] = A + (size_t)ar * NH + chunk;
    int br = wv*32 + i*8 + (lane >> 3);
    srcB[i] = Bw + (size_t)br * NH + chunk;
  }

  f32x4 acc[4][4];
  #pragma unroll
  for (int x=0;x<4;++x)
    #pragma unroll
    for (int y=0;y<4;++y) acc[x][y] = (f32x4){0.f,0.f,0.f,0.f};

  auto STAGE = [&](int bf, int kt){
    const int k0 = kt * 64;
    #pragma unroll
    for (int i = 0; i < 4; ++i){
      ASYNC16(srcA[i] + k0, &lA[bf][wv*32 + i*8][0]);
      ASYNC16(srcB[i] + k0, &lB[bf][wv*32 + i*8][0]);
    }
  };

  STAGE(0, 0);
  asm volatile("s_waitcnt vmcnt(0)" ::: "memory");
  __syncthreads();

  const int wm = (wv >> 1) * 64, wn = (wv & 1) * 64;
  const int fr = lane & 15, fq = lane >> 4;
  int cur = 0;
  for (int kt = 0; kt < 8; ++kt){
    if (kt + 1 < 8) STAGE(cur ^ 1, kt + 1);
    #pragma unroll
    for (int ks = 0; ks < 2; ++ks){
      bf16x8 af[4], bfv[4];
      #pragma unroll
      for (int mi = 0; mi < 4; ++mi)
        af[mi] = *(const bf16x8*)&lA[cur][wm + mi*16 + fr][ks*32 + fq*8];
      #pragma unroll
      for (int ni = 0; ni < 4; ++ni)
        bfv[ni] = *(const bf16x8*)&lB[cur][wn + ni*16 + fr][ks*32 + fq*8];
      #pragma unroll
      for (int mi = 0; mi < 4; ++mi)
        #pragma unroll
        for (int ni = 0; ni < 4; ++ni)
          acc[mi][ni] = __builtin_amdgcn_mfma_f32_16x16x32_bf16(af[mi], bfv[ni], acc[mi][ni], 0, 0, 0);
    }
    asm volatile("s_waitcnt vmcnt(0)" ::: "memory");
    __syncthreads();
    cur ^= 1;
  }

  // epilogue: per (mi, rr) one row per fq group; reduce over 64 cols of this wave
  float bv[4];
  #pragma unroll
  for (int ni = 0; ni < 4; ++ni) bv[ni] = bias[wn + ni*16 + fr];
  #pragma unroll
  for (int mi = 0; mi < 4; ++mi){
    #pragma unroll
    for (int rr = 0; rr < 4; ++rr){
      const int rowL = wm + mi*16 + fq*4 + rr;
      float v[4];
      #pragma unroll
      for (int ni = 0; ni < 4; ++ni) v[ni] = acc[mi][ni][rr] + bv[ni];
      // target gather
      int tk = tko[m0 + rowL];
      int rel = tk - wn;
      if (rel >= 0 && rel < 64 && fr == (rel & 15)) tgt[rowL] = v[rel >> 4];
      // group max
      float m = fmaxf(fmaxf(v[0], v[1]), fmaxf(v[2], v[3]));
      #pragma unroll
      for (int o = 1; o < 16; o <<= 1) m = fmaxf(m, __shfl_xor(m, o));
      float sm = fexp(v[0]-m) + fexp(v[1]-m) + fexp(v[2]-m) + fexp(v[3]-m);
      #pragma unroll
      for (int o = 1; o < 16; o <<= 1) sm += __shfl_xor(sm, o);
      if (fr == 0){ pmax[rowL][wv & 1] = m; psum[rowL][wv & 1] = sm; }
    }
  }
  __syncthreads();
  if (tid < 128){
    float m0h = pmax[tid][0], m1h = pmax[tid][1];
    float M = fmaxf(m0h, m1h);
    float S = psum[tid][0]*fexp(m0h - M) + psum[tid][1]*fexp(m1h - M);
    float ll = tgt[tid] - (M + flog(S));
    #pragma unroll
    for (int o = 1; o < 64; o <<= 1) ll += __shfl_xor(ll, o);
    if ((tid & 63) == 0) part[tid >> 6] = ll;
  }
  __syncthreads();
  if (tid == 0) atomicAdd(out + (m0 >> 8), part[0] + part[1]);
}

// -------- persistent GRU: 2 batches/block, 128 blocks x 512 thr (R14) ----------
// Blocks with equal slice s hold IDENTICAL weights -> serve 2 batches with the
// same 96 weight VGPRs. The two exchange chains' latencies overlap (both polls
// concurrent); compute doubles but latency is paid once per iteration.
// pair = bid&15, s = bid>>4 -> all 8 slices of a pair on XCD pair%8 (R8 L2
// locality). Protocol per batch = R11/R13 verbatim (dual-path tagged u64,
// 2-deep pipelined poll, no-drain barriers). MALL fallback keeps G16.
__global__ __launch_bounds__(512, 1) void k_gru(
    const float* __restrict__ Whh, const float* __restrict__ bhh,
    const unsigned short* __restrict__ embp,   // [NV][1536]
    const unsigned short* __restrict__ objp,   // [NB*NS][1536]
    const int* __restrict__ tokin, const int* __restrict__ pids,
    const int* __restrict__ pmask,
    const float* __restrict__ h032,
    u64* __restrict__ hx, u64* __restrict__ hxL,
    unsigned short* __restrict__ obf)
{
  const int bid = blockIdx.x;
  const int pair = bid & 15, s = bid >> 4;
  const int b0 = pair << 1, b1 = b0 | 1;
  const int tid = threadIdx.x;
  const int u = tid >> 3, r = tid & 7;
  const int jg = s * 64 + u;

  __shared__ __align__(16) unsigned int hl[2][256];
  __shared__ float xpl[2][192];
  __shared__ unsigned int pkb[64];

  half2v w0[8][4], w1[8][4], w2[8][4];
  #pragma unroll
  for (int c = 0; c < 8; ++c){
    const int kb = r*64 + ((c + r) & 7) * 8;
    const float* p0 = Whh + ((size_t)(       jg)) * NH + kb;
    const float* p1 = Whh + ((size_t)(  NH + jg)) * NH + kb;
    const float* p2 = Whh + ((size_t)(2*NH + jg)) * NH + kb;
    #pragma unroll
    for (int p = 0; p < 4; ++p){
      float2 a = *(const float2*)(p0 + 2*p);
      float2 c2 = *(const float2*)(p1 + 2*p);
      float2 d = *(const float2*)(p2 + 2*p);
      w0[c][p] = pkrtz(a.x, a.y);
      w1[c][p] = pkrtz(c2.x, c2.y);
      w2[c][p] = pkrtz(d.x, d.y);
    }
  }
  const float bh0 = bhh[jg], bh1 = bhh[NH + jg], bh2 = bhh[2*NH + jg];
  float hprev0 = h032[b0*NH + jg], hprev1 = h032[b1*NH + jg]; // r==0 lanes

  // gather roles: tid<192 -> batch0 col slot tid; tid in [192,384) -> batch1
  const int gb = (tid < 192) ? 0 : ((tid < 384) ? 1 : -1);
  const int gslot = (gb == 0) ? tid : tid - 192;
  int jcol = 0, mk = 0;
  unsigned short xe = 0, xo = 0;
  if (gb >= 0){
    const int gbb = gb ? b1 : b0;
    jcol = (gslot >> 6) * NH + s*64 + (gslot & 63);
    int tk = tokin[gbb*NT + 0];
    int pd = pids [gbb*NT + 0];
    mk     = pmask[gbb*NT + 0];
    xe = embp[(size_t)tk * 1536 + jcol];
    xo = objp[((size_t)(gbb*NS + pd)) * 1536 + jcol];
  }
  // poll role: word (tid&255) of batch (tid>>8)
  const int pb = tid >> 8, widx = tid & 255;
  const int pbb = pb ? b1 : b0;
  __syncthreads();

  for (int t = 0; t < NT; ++t){
    // consume gathered x_proj terms for step t; issue gathers for t+1
    if (gb >= 0){
      const int gbb = gb ? b1 : b0;
      xpl[gb][gslot] = bf2f(xe) + (mk ? bf2f(xo) : 0.f);
      if (t + 1 < NT){
        int tk = tokin[gbb*NT + t + 1];
        int pd = pids [gbb*NT + t + 1];
        mk     = pmask[gbb*NT + t + 1];
        xe = embp[(size_t)tk * 1536 + jcol];
        xo = objp[((size_t)(gbb*NS + pd)) * 1536 + jcol];
      }
    }
    // poll own word (2-deep pipelined, L2 fast path + MALL fallback)
    {
      const int base = (((t & 1) * NB + pbb) << 8) + widx;
      const u64* pL = hxL + base;
      const u64* pM = hx + base;
      const unsigned int want = (unsigned int)(t + 1);
      u64 v;
      u64 a  = __hip_atomic_load(pL, __ATOMIC_RELAXED, __HIP_MEMORY_SCOPE_AGENT);
      u64 b2 = __hip_atomic_load(pL, __ATOMIC_RELAXED, __HIP_MEMORY_SCOPE_AGENT);
      int it = 0;
      while (true){
        if ((unsigned int)(a >> 32) == want){ v = a; break; }
        a = b2;
        b2 = __hip_atomic_load(pL, __ATOMIC_RELAXED, __HIP_MEMORY_SCOPE_AGENT);
        if (((++it) & 7) == 0){
          u64 m = __hip_atomic_load(pM, __ATOMIC_RELAXED, __HIP_MEMORY_SCOPE_AGENT);
          if ((unsigned int)(m >> 32) == want){ v = m; break; }
        }
      }
      hl[pb][widx] = (unsigned int)v;
    }
    BAR();

    // both batches: rotated chunk loads + 2x96 fdot2 (weights shared)
    float a00=0.f, a01=0.f, a02=0.f, a10=0.f, a11=0.f, a12=0.f;
    #pragma unroll
    for (int c = 0; c < 8; ++c){
      const int g = (r << 3) + ((c + r) & 7);
      uint4 hv0 = *(const uint4*)&hl[0][g * 4];
      uint4 hv1 = *(const uint4*)&hl[1][g * 4];
      half2v h00 = __builtin_bit_cast(half2v, hv0.x);
      half2v h01 = __builtin_bit_cast(half2v, hv0.y);
      half2v h02 = __builtin_bit_cast(half2v, hv0.z);
      half2v h03 = __builtin_bit_cast(half2v, hv0.w);
      half2v h10 = __builtin_bit_cast(half2v, hv1.x);
      half2v h11 = __builtin_bit_cast(half2v, hv1.y);
      half2v h12 = __builtin_bit_cast(half2v, hv1.z);
      half2v h13 = __builtin_bit_cast(half2v, hv1.w);
      a00 = __builtin_amdgcn_fdot2(w0[c][0], h00, a00, false);
      a00 = __builtin_amdgcn_fdot2(w0[c][1], h01, a00, false);
      a00 = __builtin_amdgcn_fdot2(w0[c][2], h02, a00, false);
      a00 = __builtin_amdgcn_fdot2(w0[c][3], h03, a00, false);
      a01 = __builtin_amdgcn_fdot2(w1[c][0], h00, a01, false);
      a01 = __builtin_amdgcn_fdot2(w1[c][1], h01, a01, false);
      a01 = __builtin_amdgcn_fdot2(w1[c][2], h02, a01, false);
      a01 = __builtin_amdgcn_fdot2(w1[c][3], h03, a01, false);
      a02 = __builtin_amdgcn_fdot2(w2[c][0], h00, a02, false);
      a02 = __builtin_amdgcn_fdot2(w2[c][1], h01, a02, false);
      a02 = __builtin_amdgcn_fdot2(w2[c][2], h02, a02, false);
      a02 = __builtin_amdgcn_fdot2(w2[c][3], h03, a02, false);
      a10 = __builtin_amdgcn_fdot2(w0[c][0], h10, a10, false);
      a10 = __builtin_amdgcn_fdot2(w0[c][1], h11, a10, false);
      a10 = __builtin_amdgcn_fdot2(w0[c][2], h12, a10, false);
      a10 = __builtin_amdgcn_fdot2(w0[c][3], h13, a10, false);
      a11 = __builtin_amdgcn_fdot2(w1[c][0], h10, a11, false);
      a11 = __builtin_amdgcn_fdot2(w1[c][1], h11, a11, false);
      a11 = __builtin_amdgcn_fdot2(w1[c][2], h12, a11, false);
      a11 = __builtin_amdgcn_fdot2(w1[c][3], h13, a11, false);
      a12 = __builtin_amdgcn_fdot2(w2[c][0], h10, a12, false);
      a12 = __builtin_amdgcn_fdot2(w2[c][1], h11, a12, false);
      a12 = __builtin_amdgcn_fdot2(w2[c][2], h12, a12, false);
      a12 = __builtin_amdgcn_fdot2(w2[c][3], h13, a12, false);
    }
    a00 += __shfl_xor(a00, 1); a00 += __shfl_xor(a00, 2); a00 += __shfl_xor(a00, 4);
    a01 += __shfl_xor(a01, 1); a01 += __shfl_xor(a01, 2); a01 += __shfl_xor(a01, 4);
    a02 += __shfl_xor(a02, 1); a02 += __shfl_xor(a02, 2); a02 += __shfl_xor(a02, 4);
    a10 += __shfl_xor(a10, 1); a10 += __shfl_xor(a10, 2); a10 += __shfl_xor(a10, 4);
    a11 += __shfl_xor(a11, 1); a11 += __shfl_xor(a11, 2); a11 += __shfl_xor(a11, 4);
    a12 += __shfl_xor(a12, 1); a12 += __shfl_xor(a12, 2); a12 += __shfl_xor(a12, 4);

    float hn0 = 0.f, hn1 = 0.f;
    if (r == 0){
      float xr0 = xpl[0][u], xz0 = xpl[0][64 + u], xn0 = xpl[0][128 + u];
      float rg0 = fsigm(xr0 + a00 + bh0);
      float zg0 = fsigm(xz0 + a01 + bh1);
      float ng0 = ftanh(xn0 + rg0 * (a02 + bh2));
      hn0 = (1.f - zg0) * ng0 + zg0 * hprev0; hprev0 = hn0;
      float xr1 = xpl[1][u], xz1 = xpl[1][64 + u], xn1 = xpl[1][128 + u];
      float rg1 = fsigm(xr1 + a10 + bh0);
      float zg1 = fsigm(xz1 + a11 + bh1);
      float ng1 = ftanh(xn1 + rg1 * (a12 + bh2));
      hn1 = (1.f - zg1) * ng1 + zg1 * hprev1; hprev1 = hn1;
    }
    float hp0 = __shfl_xor(hn0, 8);  // partner unit u^1 (same r)
    float hp1 = __shfl_xor(hn1, 8);
    if (r == 0 && (u & 1) == 0){
      const u64 tg = (u64)(unsigned int)(t + 2) << 32;
      unsigned int pw0 = __builtin_bit_cast(unsigned int, pkrtz(hn0, hp0));
      unsigned int pw1 = __builtin_bit_cast(unsigned int, pkrtz(hn1, hp1));
      const int wofs = (s << 5) + (u >> 1);
      const int pb0 = ((((t + 1) & 1) * NB + b0) << 8) + wofs;
      const int pb1 = ((((t + 1) & 1) * NB + b1) << 8) + wofs;
      u64 pv0 = tg | (u64)pw0, pv1 = tg | (u64)pw1;
      st_l2(hxL + pb0, pv0);
      st_l2(hxL + pb1, pv1);
      __hip_atomic_store(hx + pb0, pv0, __ATOMIC_RELAXED, __HIP_MEMORY_SCOPE_AGENT);
      __hip_atomic_store(hx + pb1, pv1, __ATOMIC_RELAXED, __HIP_MEMORY_SCOPE_AGENT);
      pkb[(u >> 1)]      = (unsigned int)f2bf(hn0) | ((unsigned int)f2bf(hp0) << 16);
      pkb[32 + (u >> 1)] = (unsigned int)f2bf(hn1) | ((unsigned int)f2bf(hp1) << 16);
    }
    BAR();                               // loop-end barrier (no vmcnt drain)

    if (tid >= 448){
      int i = tid - 448;
      int bb = (i < 32) ? b0 : b1;
      int ii = i & 31;
      ((unsigned int*)obf)[((size_t)(bb*NT + t)) * (NH/2) + s*32 + ii] = pkb[i];
    }
  }
}

// ---------------- pointer attention + masked log-softmax gather ----------------
__global__ __launch_bounds__(256, 2) void k_ptr(
    const unsigned short* __restrict__ hd, const float* __restrict__ okp,
    const float* __restrict__ vat, const int* __restrict__ ptg,
    const int* __restrict__ pmask, float* __restrict__ out)
{
  __shared__ unsigned short okl[NS][518];
  __shared__ unsigned short hdl[16][518];
  __shared__ float vl[NH];
  __shared__ float attl[16][33];
  const int tid = threadIdx.x;
  const int b = blockIdx.x >> 4, t0 = (blockIdx.x & 15) * 16;
  for (int ii = 0; ii < 64; ++ii){
    int lin = ii*256 + tid;
    int s = lin >> 9, h = lin & 511;
    okl[s][h] = f2bf(okp[((size_t)(b*NS + s)) * NH + h]);
  }
  for (int ii = 0; ii < 32; ++ii){
    int lin = ii*256 + tid;
    int tt = lin >> 9, h = lin & 511;
    hdl[tt][h] = hd[((size_t)(b*NT + t0 + tt)) * NH + h];
  }
  vl[tid] = vat[tid]; vl[256 + tid] = vat[256 + tid];
  __syncthreads();
  #pragma unroll
  for (int pp = 0; pp < 2; ++pp){
    int p = pp*256 + tid;
    int tt = p >> 5, s = p & 31;
    float a = 0.f;
    #pragma unroll 4
    for (int h = 0; h < NH; ++h)
      a += vl[h] * ftanh(bf2f(hdl[tt][h]) + bf2f(okl[s][h]));
    attl[tt][s] = a;
  }
  __syncthreads();
  if (tid < 16){
    int tt = tid;
    float m = -1e30f;
    for (int s = 0; s < NS; ++s) m = fmaxf(m, attl[tt][s]);
    float sm = 0.f;
    for (int s = 0; s < NS; ++s) sm += fexp(attl[tt][s] - m);
    float lse = m + flog(sm);
    int g = b*NT + t0 + tt;
    float c = pmask[g] ? (attl[tt][ptg[g]] - lse) : 0.f;
    #pragma unroll
    for (int o = 1; o < 16; o <<= 1) c += __shfl_xor(c, o);
    if (tid == 0) atomicAdd(out + b, c);
  }
}

// ------------------------------- launch ---------------------------------------
extern "C" void kernel_launch(void* const* d_in, const int* in_sizes, int n_in,
                              void* d_out, int out_size, void* d_ws, size_t ws_size,
                              hipStream_t stream)
{
  (void)in_sizes; (void)n_in; (void)out_size; (void)ws_size;
  const float* embedding  = (const float*)d_in[0];
  const float* scope_enc  = (const float*)d_in[1];
  const float* spec_enc   = (const float*)d_in[2];
  const float* W_init     = (const float*)d_in[3];
  const float* b_init     = (const float*)d_in[4];
  const float* W_ih       = (const float*)d_in[5];
  const float* W_hh       = (const float*)d_in[6];
  const float* b_ih       = (const float*)d_in[7];
  const float* b_hh       = (const float*)d_in[8];
  const float* W_out      = (const float*)d_in[9];
  const float* b_out      = (const float*)d_in[10];
  const float* Wd         = (const float*)d_in[11];
  const float* We         = (const float*)d_in[12];
  const float* v_attn     = (const float*)d_in[13];
  const int* tokens_in    = (const int*)d_in[14];
  const int* tokens_out   = (const int*)d_in[15];
  const int* pointer_ids  = (const int*)d_in[16];
  const int* ptr_targets  = (const int*)d_in[17];
  const int* pointer_mask = (const int*)d_in[18];
  float* outF = (float*)d_out;

  uint8_t* wp = (uint8_t*)d_ws;
  auto carve = [&](size_t bytes)->void*{
    void* p = (void*)wp; wp += (bytes + 255) & ~(size_t)255; return p;
  };
  unsigned short* embp_bf  = (unsigned short*)carve((size_t)NV*1536*2);
  unsigned short* objp_bf  = (unsigned short*)carve((size_t)NB*NS*1536*2);
  unsigned short* o_bf     = (unsigned short*)carve((size_t)BT*NH*2);
  unsigned short* hd_bf    = (unsigned short*)carve((size_t)BT*NH*2);
  float*          okp      = (float*)carve((size_t)NB*NS*NH*4);
  unsigned short* emb_bf   = (unsigned short*)carve((size_t)NV*NH*2);
  unsigned short* scope_bf = (unsigned short*)carve((size_t)NB*NS*NH*2);
  unsigned short* Wih_bf   = (unsigned short*)carve((size_t)3*NH*2*NH*2);
  unsigned short* Wout_bf  = (unsigned short*)carve((size_t)NV*NH*2);
  unsigned short* Wd_bf    = (unsigned short*)carve((size_t)NH*NH*2);
  unsigned short* We_bf    = (unsigned short*)carve((size_t)NH*NH*2);
  float*          h032     = (float*)carve((size_t)NB*NH*4);
  u64*            hx       = (u64*)carve((size_t)2*NB*256*8);
  u64*            hxL      = (u64*)carve((size_t)2*NB*256*8);

  hipLaunchKernelGGL(k_prep, dim3(1024), dim3(256), 0, stream,
                     embedding, scope_enc, W_ih, W_out, Wd, We,
                     emb_bf, scope_bf, Wih_bf, Wout_bf, Wd_bf, We_bf,
                     hx, hxL, outF);
  hipLaunchKernelGGL(k_h0, dim3(NB), dim3(256), 0, stream, spec_enc, W_init, b_init,
                     h032, hx, hxL);
  // embproj = emb @ W_ih[:, :512]^T + b_ih   (128 x 1536, K=512)
  hipLaunchKernelGGL(k_gemm, dim3(1,12), dim3(256), 0, stream,
                     emb_bf, Wih_bf, (float*)nullptr, embp_bf,
                     b_ih, NV, 1536, NH, 1024);
  // objproj = scope @ W_ih[:, 512:]^T        (1024 x 1536, K=512)
  hipLaunchKernelGGL(k_gemm, dim3(8,12), dim3(256), 0, stream,
                     scope_bf, Wih_bf + NH, (float*)nullptr, objp_bf,
                     (const float*)nullptr, NB*NS, 1536, NH, 1024);
  // GRU scan: 128 blocks x 512 threads, 2 batches per block
  hipLaunchKernelGGL(k_gru, dim3(128), dim3(512), 0, stream,
                     W_hh, b_hh, embp_bf, objp_bf, tokens_in, pointer_ids,
                     pointer_mask, h032, hx, hxL, o_bf);
  // fused logits + log-softmax + token-LL
  hipLaunchKernelGGL(k_logll, dim3(64), dim3(256), 0, stream,
                     o_bf, Wout_bf, b_out, tokens_out, outF);
  // hd = o @ Wd^T -> bf16
  hipLaunchKernelGGL(k_gemm, dim3(64,4), dim3(256), 0, stream,
                     o_bf, Wd_bf, (float*)nullptr, hd_bf, (const float*)nullptr,
                     BT, NH, NH, NH);
  // ok = scope @ We^T -> f32
  hipLaunchKernelGGL(k_gemm, dim3(8,4), dim3(256), 0, stream,
                     scope_bf, We_bf, okp, (unsigned short*)nullptr,
                     (const float*)nullptr, NB*NS, NH, NH, NH);
  hipLaunchKernelGGL(k_ptr, dim3(512), dim3(256), 0, stream,
                     hd_bf, okp, v_attn, ptr_targets, pointer_mask, outF);
}

// Round 15
// 563.186 us; speedup vs baseline: 1.4281x; 1.4281x over previous
//
#include <hip/hip_runtime.h>
#include <stdint.h>

#define NB 32      // B
#define NT 256     // T
#define NS 32      // S
#define NH 512     // H
#define NV 128     // V
#define BT 8192    // B*T

typedef __attribute__((ext_vector_type(8))) __bf16 bf16x8;
typedef __attribute__((ext_vector_type(4))) float f32x4;
typedef __attribute__((ext_vector_type(2))) _Float16 half2v;
typedef unsigned long long u64;

typedef __attribute__((address_space(1))) const unsigned int GASU;
typedef __attribute__((address_space(3))) unsigned int LASU;
#define ASYNC16(g, l) __builtin_amdgcn_global_load_lds((GASU*)(g), (LASU*)(l), 16, 0, 0)

__device__ __forceinline__ half2v pkrtz(float a, float b){
  return __builtin_bit_cast(half2v, __builtin_amdgcn_cvt_pkrtz(a, b));
}
__device__ __forceinline__ unsigned short f2bf(float f){
  unsigned int u = __builtin_bit_cast(unsigned int, f);
  u += 0x7fffu + ((u >> 16) & 1u);
  return (unsigned short)(u >> 16);
}
__device__ __forceinline__ float bf2f(unsigned short h){
  return __builtin_bit_cast(float, ((unsigned int)h) << 16);
}
__device__ __forceinline__ float fexp(float x){ return __builtin_amdgcn_exp2f(x * 1.4426950408889634f); }
__device__ __forceinline__ float fsigm(float x){ return __builtin_amdgcn_rcpf(1.f + fexp(-x)); }
__device__ __forceinline__ float ftanh(float x){
  float t = __builtin_amdgcn_exp2f(x * 2.8853900817779268f);
  return (t - 1.f) * __builtin_amdgcn_rcpf(t + 1.f);
}
__device__ __forceinline__ float flog(float x){ return __builtin_amdgcn_logf(x) * 0.6931471805599453f; }

// L2 fast-path store: plain store (lands in the producer XCD's L2).
__device__ __forceinline__ void st_l2(u64* p, u64 v){
  asm volatile("global_store_dwordx2 %0, %1, off" :: "v"(p), "v"(v) : "memory");
}

// barrier WITHOUT the vmcnt(0) drain __syncthreads would emit (rule #18 fenced)
#define BAR() do{ \
  asm volatile("s_waitcnt lgkmcnt(0)" ::: "memory"); \
  __builtin_amdgcn_sched_barrier(0); \
  __builtin_amdgcn_s_barrier(); \
  __builtin_amdgcn_sched_barrier(0); \
}while(0)

// ------ fp32 -> bf16 conversions of tables/weights + init duties (merged) ------
__global__ void k_prep(const float* __restrict__ emb, const float* __restrict__ scope,
                       const float* __restrict__ Wih, const float* __restrict__ Wout,
                       const float* __restrict__ Wd,  const float* __restrict__ We,
                       unsigned short* e_o, unsigned short* s_o, unsigned short* wi_o,
                       unsigned short* wo_o, unsigned short* wd_o, unsigned short* we_o,
                       u64* hx, u64* hxL, float* out){
  int g = blockIdx.x*256 + threadIdx.x, gs = gridDim.x*256;
  if (g < 2*NB*256){
    hx[g] = 0ull;
    __hip_atomic_store(hxL + g, 0ull, __ATOMIC_RELAXED, __HIP_MEMORY_SCOPE_AGENT);
  }
  if (g < NB) out[g] = 0.f;
  for (int i=g; i<NV*NH;      i+=gs) e_o[i]  = f2bf(emb[i]);
  for (int i=g; i<NB*NS*NH;   i+=gs) s_o[i]  = f2bf(scope[i]);
  for (int i=g; i<3*NH*2*NH;  i+=gs) wi_o[i] = f2bf(Wih[i]);
  for (int i=g; i<NV*NH;      i+=gs) wo_o[i] = f2bf(Wout[i]);
  for (int i=g; i<NH*NH;      i+=gs) wd_o[i] = f2bf(Wd[i]);
  for (int i=g; i<NH*NH;      i+=gs) we_o[i] = f2bf(We[i]);
}

// ---------------- h0 = spec_enc @ W_init^T + b_init ----------------------------
// writes f32 copy and tagged packed-f16 exchange words (tag 1, parity-0 buffer)
__global__ void k_h0(const float* __restrict__ spec, const float* __restrict__ Winit,
                     const float* __restrict__ binit, float* __restrict__ h032,
                     u64* __restrict__ hx, u64* __restrict__ hxL){
  const int b = blockIdx.x, tid = threadIdx.x, lane = tid & 63, w = tid >> 6;
  __shared__ float sp[NH];
  __shared__ float hres[NH];
  if (tid < 128) *(float4*)&sp[tid*4] = *(const float4*)(spec + b*NH + tid*4);
  __syncthreads();
  for (int i = 0; i < 128; ++i){
    int j = w * 128 + i;
    const float4* wr = (const float4*)(Winit + (size_t)j * NH);
    float4 x0 = wr[lane*2], x1 = wr[lane*2 + 1];
    float p = x0.x*sp[lane*8]   + x0.y*sp[lane*8+1] + x0.z*sp[lane*8+2] + x0.w*sp[lane*8+3]
            + x1.x*sp[lane*8+4] + x1.y*sp[lane*8+5] + x1.z*sp[lane*8+6] + x1.w*sp[lane*8+7];
    #pragma unroll
    for (int o = 1; o < 64; o <<= 1) p += __shfl_xor(p, o);
    if (lane == 0){
      float v = p + binit[j];
      h032[b*NH + j] = v;
      hres[j] = v;
    }
  }
  __syncthreads();
  if (tid < 256){
    unsigned int pw = __builtin_bit_cast(unsigned int, pkrtz(hres[2*tid], hres[2*tid+1]));
    u64 pv = (1ull << 32) | (u64)pw;           // tag(h_0) = 1
    __hip_atomic_store(hx + b*256 + tid, pv, __ATOMIC_RELAXED, __HIP_MEMORY_SCOPE_AGENT);
    __hip_atomic_store(hxL + b*256 + tid, pv, __ATOMIC_RELAXED, __HIP_MEMORY_SCOPE_AGENT);
  }
}

// ------- MFMA bf16 GEMM: C = A @ Bw^T (+bias), 128x128 tile, B row-stride ldb --
__global__ __launch_bounds__(256, 2) void k_gemm(
    const unsigned short* __restrict__ A, const unsigned short* __restrict__ Bw,
    float* __restrict__ Cf, unsigned short* __restrict__ Cbf,
    const float* __restrict__ bias, int M, int N, int K, int ldb)
{
  __shared__ unsigned short lA[2][128][64];
  __shared__ unsigned short lB[2][128][64];
  const int tid = threadIdx.x, lane = tid & 63, wv = tid >> 6;
  const int m0 = blockIdx.x * 128, n0 = blockIdx.y * 128;

  const unsigned short* srcA[4];
  const unsigned short* srcB[4];
  #pragma unroll
  for (int i = 0; i < 4; ++i){
    int ar = m0 + wv*32 + i*8 + (lane >> 3);
    int chunk = (lane & 7) * 8;
    srcA[i] = A + (size_t)ar * K + chunk;
    int br = n0 + wv*32 + i*8 + (lane >> 3);
    srcB[i] = Bw + (size_t)br * ldb + chunk;
  }

  f32x4 acc[4][4];
  #pragma unroll
  for (int x=0;x<4;++x)
    #pragma unroll
    for (int y=0;y<4;++y) acc[x][y] = (f32x4){0.f,0.f,0.f,0.f};

  auto STAGE = [&](int bf, int kt){
    const int k0 = kt * 64;
    #pragma unroll
    for (int i = 0; i < 4; ++i){
      ASYNC16(srcA[i] + k0, &lA[bf][wv*32 + i*8][0]);
      ASYNC16(srcB[i] + k0, &lB[bf][wv*32 + i*8][0]);
    }
  };

  STAGE(0, 0);
  asm volatile("s_waitcnt vmcnt(0)" ::: "memory");
  __syncthreads();

  const int wm = (wv >> 1) * 64, wn = (wv & 1) * 64;
  const int fr = lane & 15, fq = lane >> 4;
  const int nt = K >> 6;
  int cur = 0;
  for (int kt = 0; kt < nt; ++kt){
    if (kt + 1 < nt) STAGE(cur ^ 1, kt + 1);
    #pragma unroll
    for (int ks = 0; ks < 2; ++ks){
      bf16x8 af[4], bfv[4];
      #pragma unroll
      for (int mi = 0; mi < 4; ++mi)
        af[mi] = *(const bf16x8*)&lA[cur][wm + mi*16 + fr][ks*32 + fq*8];
      #pragma unroll
      for (int ni = 0; ni < 4; ++ni)
        bfv[ni] = *(const bf16x8*)&lB[cur][wn + ni*16 + fr][ks*32 + fq*8];
      #pragma unroll
      for (int mi = 0; mi < 4; ++mi)
        #pragma unroll
        for (int ni = 0; ni < 4; ++ni)
          acc[mi][ni] = __builtin_amdgcn_mfma_f32_16x16x32_bf16(af[mi], bfv[ni], acc[mi][ni], 0, 0, 0);
    }
    asm volatile("s_waitcnt vmcnt(0)" ::: "memory");
    __syncthreads();
    cur ^= 1;
  }

  #pragma unroll
  for (int mi = 0; mi < 4; ++mi){
    #pragma unroll
    for (int ni = 0; ni < 4; ++ni){
      int col = n0 + wn + ni*16 + fr;
      float bv = bias ? bias[col] : 0.f;
      #pragma unroll
      for (int rr = 0; rr < 4; ++rr){
        int row = m0 + wm + mi*16 + fq*4 + rr;
        float v = acc[mi][ni][rr] + bv;
        if (Cbf) Cbf[(size_t)row * N + col] = f2bf(v);
        else     Cf [(size_t)row * N + col] = v;
      }
    }
  }
}

// ------ FUSED logits GEMM + log-softmax + target gather + per-batch sum --------
__global__ __launch_bounds__(256, 2) void k_logll(
    const unsigned short* __restrict__ A, const unsigned short* __restrict__ Bw,
    const float* __restrict__ bias, const int* __restrict__ tko,
    float* __restrict__ out)
{
  __shared__ unsigned short lA[2][128][64];
  __shared__ unsigned short lB[2][128][64];
  __shared__ float pmax[128][2], psum[128][2], tgt[128], part[2];
  const int tid = threadIdx.x, lane = tid & 63, wv = tid >> 6;
  const int m0 = blockIdx.x * 128;

  const unsigned short* srcA[4];
  const unsigned short* srcB[4];
  #pragma unroll
  for (int i = 0; i < 4; ++i){
    int ar = m0 + wv*32 + i*8 + (lane >> 3);
    int chunk = (lane & 7) * 8;
    srcA[i] = A + (size_t)ar * NH + chunk;
    int br = wv*32 + i*8 + (lane >> 3);
    srcB[i] = Bw + (size_t)br * NH + chunk;
  }

  f32x4 acc[4][4];
  #pragma unroll
  for (int x=0;x<4;++x)
    #pragma unroll
    for (int y=0;y<4;++y) acc[x][y] = (f32x4){0.f,0.f,0.f,0.f};

  auto STAGE = [&](int bf, int kt){
    const int k0 = kt * 64;
    #pragma unroll
    for (int i = 0; i < 4; ++i){
      ASYNC16(srcA[i] + k0, &lA[bf][wv*32 + i*8][0]);
      ASYNC16(srcB[i] + k0, &lB[bf][wv*32 + i*8][0]);
    }
  };

  STAGE(0, 0);
  asm volatile("s_waitcnt vmcnt(0)" ::: "memory");
  __syncthreads();

  const int wm = (wv >> 1) * 64, wn = (wv & 1) * 64;
  const int fr = lane & 15, fq = lane >> 4;
  int cur = 0;
  for (int kt = 0; kt < 8; ++kt){
    if (kt + 1 < 8) STAGE(cur ^ 1, kt + 1);
    #pragma unroll
    for (int ks = 0; ks < 2; ++ks){
      bf16x8 af[4], bfv[4];
      #pragma unroll
      for (int mi = 0; mi < 4; ++mi)
        af[mi] = *(const bf16x8*)&lA[cur][wm + mi*16 + fr][ks*32 + fq*8];
      #pragma unroll
      for (int ni = 0; ni < 4; ++ni)
        bfv[ni] = *(const bf16x8*)&lB[cur][wn + ni*16 + fr][ks*32 + fq*8];
      #pragma unroll
      for (int mi = 0; mi < 4; ++mi)
        #pragma unroll
        for (int ni = 0; ni < 4; ++ni)
          acc[mi][ni] = __builtin_amdgcn_mfma_f32_16x16x32_bf16(af[mi], bfv[ni], acc[mi][ni], 0, 0, 0);
    }
    asm volatile("s_waitcnt vmcnt(0)" ::: "memory");
    __syncthreads();
    cur ^= 1;
  }

  float bv[4];
  #pragma unroll
  for (int ni = 0; ni < 4; ++ni) bv[ni] = bias[wn + ni*16 + fr];
  #pragma unroll
  for (int mi = 0; mi < 4; ++mi){
    #pragma unroll
    for (int rr = 0; rr < 4; ++rr){
      const int rowL = wm + mi*16 + fq*4 + rr;
      float v[4];
      #pragma unroll
      for (int ni = 0; ni < 4; ++ni) v[ni] = acc[mi][ni][rr] + bv[ni];
      int tk = tko[m0 + rowL];
      int rel = tk - wn;
      if (rel >= 0 && rel < 64 && fr == (rel & 15)) tgt[rowL] = v[rel >> 4];
      float m = fmaxf(fmaxf(v[0], v[1]), fmaxf(v[2], v[3]));
      #pragma unroll
      for (int o = 1; o < 16; o <<= 1) m = fmaxf(m, __shfl_xor(m, o));
      float sm = fexp(v[0]-m) + fexp(v[1]-m) + fexp(v[2]-m) + fexp(v[3]-m);
      #pragma unroll
      for (int o = 1; o < 16; o <<= 1) sm += __shfl_xor(sm, o);
      if (fr == 0){ pmax[rowL][wv & 1] = m; psum[rowL][wv & 1] = sm; }
    }
  }
  __syncthreads();
  if (tid < 128){
    float m0h = pmax[tid][0], m1h = pmax[tid][1];
    float M = fmaxf(m0h, m1h);
    float S = psum[tid][0]*fexp(m0h - M) + psum[tid][1]*fexp(m1h - M);
    float ll = tgt[tid] - (M + flog(S));
    #pragma unroll
    for (int o = 1; o < 64; o <<= 1) ll += __shfl_xor(ll, o);
    if ((tid & 63) == 0) part[tid >> 6] = ll;
  }
  __syncthreads();
  if (tid == 0) atomicAdd(out + (m0 >> 8), part[0] + part[1]);
}

// ---------------- persistent GRU: 32 batches x 8 slices, 512 thr (R13) ---------
__global__ __launch_bounds__(512, 1) void k_gru(
    const float* __restrict__ Whh, const float* __restrict__ bhh,
    const unsigned short* __restrict__ embp,   // [NV][1536]
    const unsigned short* __restrict__ objp,   // [NB*NS][1536]
    const int* __restrict__ tokin, const int* __restrict__ pids,
    const int* __restrict__ pmask,
    const float* __restrict__ h032,
    u64* __restrict__ hx,                 // [2][NB][256] tagged pairs (MALL)
    u64* __restrict__ hxL,                // [2][NB][256] tagged pairs (L2 fast)
    unsigned short* __restrict__ obf)
{
  const int bid = blockIdx.x;
  const int b = bid & 31, s = bid >> 5;   // all slices of batch b on one XCD
  const int tid = threadIdx.x;
  const int u = tid >> 3, r = tid & 7;
  const int jg = s * 64 + u;

  __shared__ __align__(16) unsigned int hl[256];   // 512 halfs of h_t
  __shared__ float xpl[192];
  __shared__ unsigned int pkb[32];   // own slice packed bf16 pairs (for obf)

  half2v w0[8][4], w1[8][4], w2[8][4];
  #pragma unroll
  for (int c = 0; c < 8; ++c){
    const int kb = r*64 + ((c + r) & 7) * 8;
    const float* p0 = Whh + ((size_t)(       jg)) * NH + kb;
    const float* p1 = Whh + ((size_t)(  NH + jg)) * NH + kb;
    const float* p2 = Whh + ((size_t)(2*NH + jg)) * NH + kb;
    #pragma unroll
    for (int p = 0; p < 4; ++p){
      float2 a = *(const float2*)(p0 + 2*p);
      float2 c2 = *(const float2*)(p1 + 2*p);
      float2 d = *(const float2*)(p2 + 2*p);
      w0[c][p] = pkrtz(a.x, a.y);
      w1[c][p] = pkrtz(c2.x, c2.y);
      w2[c][p] = pkrtz(d.x, d.y);
    }
  }
  const float bh0 = bhh[jg], bh1 = bhh[NH + jg], bh2 = bhh[2*NH + jg];
  float hprev = h032[b*NH + jg];   // meaningful on r==0 lanes only

  // loader state: gathered x_proj terms for the upcoming step
  unsigned short xe = 0, xo = 0; int mk = 0;
  int jcol = 0;
  if (tid >= 256 && tid < 448){
    int idx = tid - 256;
    jcol = (idx >> 6) * NH + s*64 + (idx & 63);      // col in [0,1536)
    int tk = tokin[b*NT + 0];
    int pd = pids [b*NT + 0];
    mk     = pmask[b*NT + 0];
    xe = embp[(size_t)tk * 1536 + jcol];
    xo = objp[((size_t)(b*NS + pd)) * 1536 + jcol];
  }
  __syncthreads();

  for (int t = 0; t < NT; ++t){
    if (tid < 256){
      const int base = (((t & 1) * NB + b) << 8) + tid;
      const u64* pL = hxL + base;
      const u64* pM = hx + base;
      const unsigned int want = (unsigned int)(t + 1);
      u64 v;
      u64 a  = __hip_atomic_load(pL, __ATOMIC_RELAXED, __HIP_MEMORY_SCOPE_AGENT);
      u64 b2 = __hip_atomic_load(pL, __ATOMIC_RELAXED, __HIP_MEMORY_SCOPE_AGENT);
      int it = 0;
      while (true){
        if ((unsigned int)(a >> 32) == want){ v = a; break; }
        a = b2;
        b2 = __hip_atomic_load(pL, __ATOMIC_RELAXED, __HIP_MEMORY_SCOPE_AGENT);
        if (((++it) & 7) == 0){
          u64 m = __hip_atomic_load(pM, __ATOMIC_RELAXED, __HIP_MEMORY_SCOPE_AGENT);
          if ((unsigned int)(m >> 32) == want){ v = m; break; }
        }
      }
      hl[tid] = (unsigned int)v;
    } else if (tid < 448){
      int idx = tid - 256;
      xpl[idx] = bf2f(xe) + (mk ? bf2f(xo) : 0.f);   // consume step t's terms
      if (t + 1 < NT){                                // gather for step t+1
        int tk = tokin[b*NT + t + 1];
        int pd = pids [b*NT + t + 1];
        mk     = pmask[b*NT + t + 1];
        xe = embp[(size_t)tk * 1536 + jcol];
        xo = objp[((size_t)(b*NS + pd)) * 1536 + jcol];
      }
    }
    BAR();

    float a0 = 0.f, a1 = 0.f, a2 = 0.f;
    half2v hch[8][4];
    #pragma unroll
    for (int c = 0; c < 8; ++c){
      const int g = (r << 3) + ((c + r) & 7);
      uint4 hv = *(const uint4*)&hl[g * 4];
      hch[c][0] = __builtin_bit_cast(half2v, hv.x);
      hch[c][1] = __builtin_bit_cast(half2v, hv.y);
      hch[c][2] = __builtin_bit_cast(half2v, hv.z);
      hch[c][3] = __builtin_bit_cast(half2v, hv.w);
    }
    #pragma unroll
    for (int c = 0; c < 8; ++c){
      #pragma unroll
      for (int p = 0; p < 4; ++p){
        a0 = __builtin_amdgcn_fdot2(w0[c][p], hch[c][p], a0, false);
        a1 = __builtin_amdgcn_fdot2(w1[c][p], hch[c][p], a1, false);
        a2 = __builtin_amdgcn_fdot2(w2[c][p], hch[c][p], a2, false);
      }
    }
    a0 += __shfl_xor(a0, 1); a0 += __shfl_xor(a0, 2); a0 += __shfl_xor(a0, 4);
    a1 += __shfl_xor(a1, 1); a1 += __shfl_xor(a1, 2); a1 += __shfl_xor(a1, 4);
    a2 += __shfl_xor(a2, 1); a2 += __shfl_xor(a2, 2); a2 += __shfl_xor(a2, 4);

    float hnew = 0.f;
    if (r == 0){
      float xr = xpl[u], xz = xpl[64 + u], xn = xpl[128 + u];
      float rg = fsigm(xr + a0 + bh0);
      float zg = fsigm(xz + a1 + bh1);
      float ng = ftanh(xn + rg * (a2 + bh2));
      hnew = (1.f - zg) * ng + zg * hprev;
      hprev = hnew;
    }
    float hpart = __shfl_xor(hnew, 8);   // partner unit u^1 (same r)
    if (r == 0 && (u & 1) == 0){
      unsigned int pw = __builtin_bit_cast(unsigned int, pkrtz(hnew, hpart));
      u64 pv = ((u64)(unsigned int)(t + 2) << 32) | (u64)pw;  // tag(h_{t+1}) = t+2
      const int dst = ((((t + 1) & 1) * NB + b) << 8) + (s << 5) + (u >> 1);
      st_l2(hxL + dst, pv);                                    // fast path first
      __hip_atomic_store(hx + dst, pv,
                         __ATOMIC_RELAXED, __HIP_MEMORY_SCOPE_AGENT);
      pkb[u >> 1] = (unsigned int)f2bf(hnew) | ((unsigned int)f2bf(hpart) << 16);
    }
    BAR();                               // loop-end barrier (no vmcnt drain)

    if (tid >= 448 && tid < 480){
      int i = tid - 448;
      ((unsigned int*)obf)[((size_t)(b*NT + t)) * (NH/2) + s*32 + i] = pkb[i];
    }
  }
}

// ---------------- pointer attention + masked log-softmax gather ----------------
__global__ __launch_bounds__(256, 2) void k_ptr(
    const unsigned short* __restrict__ hd, const float* __restrict__ okp,
    const float* __restrict__ vat, const int* __restrict__ ptg,
    const int* __restrict__ pmask, float* __restrict__ out)
{
  __shared__ unsigned short okl[NS][518];
  __shared__ unsigned short hdl[16][518];
  __shared__ float vl[NH];
  __shared__ float attl[16][33];
  const int tid = threadIdx.x;
  const int b = blockIdx.x >> 4, t0 = (blockIdx.x & 15) * 16;
  for (int ii = 0; ii < 64; ++ii){
    int lin = ii*256 + tid;
    int s = lin >> 9, h = lin & 511;
    okl[s][h] = f2bf(okp[((size_t)(b*NS + s)) * NH + h]);
  }
  for (int ii = 0; ii < 32; ++ii){
    int lin = ii*256 + tid;
    int tt = lin >> 9, h = lin & 511;
    hdl[tt][h] = hd[((size_t)(b*NT + t0 + tt)) * NH + h];
  }
  vl[tid] = vat[tid]; vl[256 + tid] = vat[256 + tid];
  __syncthreads();
  #pragma unroll
  for (int pp = 0; pp < 2; ++pp){
    int p = pp*256 + tid;
    int tt = p >> 5, s = p & 31;
    float a = 0.f;
    #pragma unroll 4
    for (int h = 0; h < NH; ++h)
      a += vl[h] * ftanh(bf2f(hdl[tt][h]) + bf2f(okl[s][h]));
    attl[tt][s] = a;
  }
  __syncthreads();
  if (tid < 16){
    int tt = tid;
    float m = -1e30f;
    for (int s = 0; s < NS; ++s) m = fmaxf(m, attl[tt][s]);
    float sm = 0.f;
    for (int s = 0; s < NS; ++s) sm += fexp(attl[tt][s] - m);
    float lse = m + flog(sm);
    int g = b*NT + t0 + tt;
    float c = pmask[g] ? (attl[tt][ptg[g]] - lse) : 0.f;
    #pragma unroll
    for (int o = 1; o < 16; o <<= 1) c += __shfl_xor(c, o);
    if (tid == 0) atomicAdd(out + b, c);
  }
}

// ------------------------------- launch ---------------------------------------
extern "C" void kernel_launch(void* const* d_in, const int* in_sizes, int n_in,
                              void* d_out, int out_size, void* d_ws, size_t ws_size,
                              hipStream_t stream)
{
  (void)in_sizes; (void)n_in; (void)out_size; (void)ws_size;
  const float* embedding  = (const float*)d_in[0];
  const float* scope_enc  = (const float*)d_in[1];
  const float* spec_enc   = (const float*)d_in[2];
  const float* W_init     = (const float*)d_in[3];
  const float* b_init     = (const float*)d_in[4];
  const float* W_ih       = (const float*)d_in[5];
  const float* W_hh       = (const float*)d_in[6];
  const float* b_ih       = (const float*)d_in[7];
  const float* b_hh       = (const float*)d_in[8];
  const float* W_out      = (const float*)d_in[9];
  const float* b_out      = (const float*)d_in[10];
  const float* Wd         = (const float*)d_in[11];
  const float* We         = (const float*)d_in[12];
  const float* v_attn     = (const float*)d_in[13];
  const int* tokens_in    = (const int*)d_in[14];
  const int* tokens_out   = (const int*)d_in[15];
  const int* pointer_ids  = (const int*)d_in[16];
  const int* ptr_targets  = (const int*)d_in[17];
  const int* pointer_mask = (const int*)d_in[18];
  float* outF = (float*)d_out;

  uint8_t* wp = (uint8_t*)d_ws;
  auto carve = [&](size_t bytes)->void*{
    void* p = (void*)wp; wp += (bytes + 255) & ~(size_t)255; return p;
  };
  unsigned short* embp_bf  = (unsigned short*)carve((size_t)NV*1536*2);
  unsigned short* objp_bf  = (unsigned short*)carve((size_t)NB*NS*1536*2);
  unsigned short* o_bf     = (unsigned short*)carve((size_t)BT*NH*2);
  unsigned short* hd_bf    = (unsigned short*)carve((size_t)BT*NH*2);
  float*          okp      = (float*)carve((size_t)NB*NS*NH*4);
  unsigned short* emb_bf   = (unsigned short*)carve((size_t)NV*NH*2);
  unsigned short* scope_bf = (unsigned short*)carve((size_t)NB*NS*NH*2);
  unsigned short* Wih_bf   = (unsigned short*)carve((size_t)3*NH*2*NH*2);
  unsigned short* Wout_bf  = (unsigned short*)carve((size_t)NV*NH*2);
  unsigned short* Wd_bf    = (unsigned short*)carve((size_t)NH*NH*2);
  unsigned short* We_bf    = (unsigned short*)carve((size_t)NH*NH*2);
  float*          h032     = (float*)carve((size_t)NB*NH*4);
  u64*            hx       = (u64*)carve((size_t)2*NB*256*8);
  u64*            hxL      = (u64*)carve((size_t)2*NB*256*8);

  hipLaunchKernelGGL(k_prep, dim3(1024), dim3(256), 0, stream,
                     embedding, scope_enc, W_ih, W_out, Wd, We,
                     emb_bf, scope_bf, Wih_bf, Wout_bf, Wd_bf, We_bf,
                     hx, hxL, outF);
  hipLaunchKernelGGL(k_h0, dim3(NB), dim3(256), 0, stream, spec_enc, W_init, b_init,
                     h032, hx, hxL);
  // embproj = emb @ W_ih[:, :512]^T + b_ih   (128 x 1536, K=512)
  hipLaunchKernelGGL(k_gemm, dim3(1,12), dim3(256), 0, stream,
                     emb_bf, Wih_bf, (float*)nullptr, embp_bf,
                     b_ih, NV, 1536, NH, 1024);
  // objproj = scope @ W_ih[:, 512:]^T        (1024 x 1536, K=512)
  hipLaunchKernelGGL(k_gemm, dim3(8,12), dim3(256), 0, stream,
                     scope_bf, Wih_bf + NH, (float*)nullptr, objp_bf,
                     (const float*)nullptr, NB*NS, 1536, NH, 1024);
  // GRU scan (persistent, 256 blocks x 512 threads), x_proj gathered on the fly
  hipLaunchKernelGGL(k_gru, dim3(256), dim3(512), 0, stream,
                     W_hh, b_hh, embp_bf, objp_bf, tokens_in, pointer_ids,
                     pointer_mask, h032, hx, hxL, o_bf);
  // fused logits + log-softmax + token-LL
  hipLaunchKernelGGL(k_logll, dim3(64), dim3(256), 0, stream,
                     o_bf, Wout_bf, b_out, tokens_out, outF);
  // hd = o @ Wd^T -> bf16
  hipLaunchKernelGGL(k_gemm, dim3(64,4), dim3(256), 0, stream,
                     o_bf, Wd_bf, (float*)nullptr, hd_bf, (const float*)nullptr,
                     BT, NH, NH, NH);
  // ok = scope @ We^T -> f32
  hipLaunchKernelGGL(k_gemm, dim3(8,4), dim3(256), 0, stream,
                     scope_bf, We_bf, okp, (unsigned short*)nullptr,
                     (const float*)nullptr, NB*NS, NH, NH, NH);
  hipLaunchKernelGGL(k_ptr, dim3(512), dim3(256), 0, stream,
                     hd_bf, okp, v_attn, ptr_targets, pointer_mask, outF);
}